// Round 12
// baseline (389.503 us; speedup 1.0000x reference)
//
#include <hip/hip_runtime.h>

#define NN 100000
#define EE 1600000
#define BSHIFT 9
#define NBKT ((NN + 511) / 512)          // 196
#define CAP 10240                         // per-bucket capacity (avg 8163)
#define CHUNK 2048
#define NBLKA ((EE + CHUNK - 1) / CHUNK)  // 782

typedef float f32x4 __attribute__((ext_vector_type(4)));
typedef float f32x2 __attribute__((ext_vector_type(2)));
typedef short s16x8 __attribute__((ext_vector_type(8)));

__device__ __forceinline__ ushort f2bf(float x) {      // f32 -> bf16 bits, RNE
  uint u = __float_as_uint(x);
  return (ushort)((u + 0x7fffu + ((u >> 16) & 1u)) >> 16);
}
__device__ __forceinline__ uint pack2bf(float x, float y) {
  return (uint)f2bf(x) | ((uint)f2bf(y) << 16);
}
__device__ __forceinline__ float bflo(uint p) { return __uint_as_float(p << 16); }
__device__ __forceinline__ float bfhi(uint p) { return __uint_as_float(p & 0xffff0000u); }

// ---------------- MFMA GEMM: A[N,128] @ W[128,M] ----------------
// ELER==0: write f32 out + bias (classifier).
// ELER>0 : stage tile in LDS -> fused el/er (ELER heads) + fp8 e4m3 feat table.
template<int M, bool ABF, int ELER>
__global__ __launch_bounds__(256) void gemm_mfma(const void* __restrict__ Av,
    const float* __restrict__ W, const float* __restrict__ bias,
    float* __restrict__ outf, ushort* __restrict__ feat8s,
    const float* __restrict__ al, const float* __restrict__ ar,
    float* __restrict__ el, float* __restrict__ er, int N) {
  __shared__ ushort Wt[M * 136];                 // W^T bf16; reused as output stage for ELER
  const int tid = threadIdx.x;
  for (int idx = tid; idx < 128 * M; idx += 256) {
    int k = idx / M, c = idx - k * M;
    Wt[c * 136 + k] = f2bf(W[idx]);
  }
  __syncthreads();
  const int wid = tid >> 6, lane = tid & 63;
  const int rl = lane & 15, grp = lane >> 4;
  const long row0 = (long)blockIdx.x * 128;

  s16x8 af[2][4];
#pragma unroll
  for (int rt = 0; rt < 2; ++rt) {
    long row = row0 + rt * 64 + wid * 16 + rl;
    if (row >= N) row = N - 1;
    if (ABF) {
      const s16x8* Ar = (const s16x8*)((const ushort*)Av + row * 128);
#pragma unroll
      for (int ks = 0; ks < 4; ++ks) af[rt][ks] = Ar[ks * 4 + grp];
    } else {
      const float4* Ar = (const float4*)((const float*)Av + row * 128);
#pragma unroll
      for (int ks = 0; ks < 4; ++ks) {
        float4 a0 = Ar[ks * 8 + grp * 2];
        float4 a1 = Ar[ks * 8 + grp * 2 + 1];
        s16x8 f;
        f[0] = (short)f2bf(a0.x); f[1] = (short)f2bf(a0.y);
        f[2] = (short)f2bf(a0.z); f[3] = (short)f2bf(a0.w);
        f[4] = (short)f2bf(a1.x); f[5] = (short)f2bf(a1.y);
        f[6] = (short)f2bf(a1.z); f[7] = (short)f2bf(a1.w);
        af[rt][ks] = f;
      }
    }
  }
  const int NT = M / 16;
  f32x4 acc[2][NT];
#pragma unroll
  for (int rt = 0; rt < 2; ++rt)
#pragma unroll
    for (int ct = 0; ct < NT; ++ct) acc[rt][ct] = (f32x4)(0.f);

#pragma unroll
  for (int ct = 0; ct < NT; ++ct) {
#pragma unroll
    for (int ks = 0; ks < 4; ++ks) {
      s16x8 bf = *(const s16x8*)&Wt[(ct * 16 + rl) * 136 + ks * 32 + grp * 8];
      acc[0][ct] = __builtin_amdgcn_mfma_f32_16x16x32_bf16(af[0][ks], bf, acc[0][ct], 0, 0, 0);
      acc[1][ct] = __builtin_amdgcn_mfma_f32_16x16x32_bf16(af[1][ks], bf, acc[1][ct], 0, 0, 0);
    }
  }

  if (ELER > 0) __syncthreads();   // everyone done reading Wt before reuse as stage

#pragma unroll
  for (int rt = 0; rt < 2; ++rt) {
#pragma unroll
    for (int ct = 0; ct < NT; ++ct) {
      int col = ct * 16 + rl;
      float bb = (ELER == 0) ? bias[col] : 0.f;
#pragma unroll
      for (int j = 0; j < 4; ++j) {
        int lrow = rt * 64 + wid * 16 + grp * 4 + j;
        long grow = row0 + lrow;
        if (ELER > 0) {
          Wt[lrow * 128 + col] = f2bf(acc[rt][ct][j]);   // stage only
        } else if (grow < N) {
          outf[grow * M + col] = acc[rt][ct][j] + bb;
        }
      }
    }
  }

  if (ELER > 0) {
    __syncthreads();
    const uint* stage = (const uint*)Wt;           // [128][64] packed bf16 pairs
    float2 a2 = ((const float2*)al)[lane];
    float2 r2 = ((const float2*)ar)[lane];
    for (int rr = 0; rr < 32; ++rr) {
      int lrow = wid * 32 + rr;
      long grow = row0 + lrow;
      uint p = stage[lrow * 64 + lane];
      float x0 = bflo(p), x1 = bfhi(p);
      int pk8 = __builtin_amdgcn_cvt_pk_fp8_f32(x0, x1, 0, false);
      if (grow < N) feat8s[grow * 64 + lane] = (ushort)pk8;
      float pl = x0 * a2.x + x1 * a2.y;
      float pr = x0 * r2.x + x1 * r2.y;
      if (ELER == 4) {
#pragma unroll
        for (int m = 8; m; m >>= 1) {
          pl += __shfl_xor(pl, m, 16);
          pr += __shfl_xor(pr, m, 16);
        }
        if ((lane & 15) == 0 && grow < N) {
          el[grow * 4 + (lane >> 4)] = pl;
          er[grow * 4 + (lane >> 4)] = pr;
        }
      } else {
#pragma unroll
        for (int m = 32; m; m >>= 1) {
          pl += __shfl_xor(pl, m, 64);
          pr += __shfl_xor(pr, m, 64);
        }
        if (lane == 0 && grow < N) { el[grow] = pl; er[grow] = pr; }
      }
    }
  }
}

// ------------- edge weights, edge-parallel & coalesced -------------
template<int HEADS>
__global__ __launch_bounds__(256) void wcomp(const int* __restrict__ ssrc,
    const int* __restrict__ sdst, const float* __restrict__ el,
    const float* __restrict__ er, float* __restrict__ wcsr) {
  int e = blockIdx.x * 256 + threadIdx.x;
  if (e >= EE) return;
  int sn = ssrc[e], dn = sdst[e];
  if (HEADS == 4) {
    float4 l4 = ((const float4*)el)[sn];
    float4 r4 = ((const float4*)er)[dn];
    float4 w;
    float ev;
    ev = l4.x + r4.x; ev = fmaxf(ev, 0.f) + 0.2f * fminf(ev, 0.f); w.x = __expf(ev);
    ev = l4.y + r4.y; ev = fmaxf(ev, 0.f) + 0.2f * fminf(ev, 0.f); w.y = __expf(ev);
    ev = l4.z + r4.z; ev = fmaxf(ev, 0.f) + 0.2f * fminf(ev, 0.f); w.z = __expf(ev);
    ev = l4.w + r4.w; ev = fmaxf(ev, 0.f) + 0.2f * fminf(ev, 0.f); w.w = __expf(ev);
    ((float4*)wcsr)[e] = w;
  } else {
    float ev = el[sn] + er[dn];
    ev = fmaxf(ev, 0.f) + 0.2f * fminf(ev, 0.f);
    wcsr[e] = __expf(ev);
  }
}

// ---------------- CSR build: bucketed counting sort (packed 32-bit records) ----------------
__global__ __launch_bounds__(256) void k_partA(const int* __restrict__ src,
    const int* __restrict__ dst, uint* __restrict__ bcnt, uint* __restrict__ tmp) {
  __shared__ uint hist[NBKT], excl[NBKT], gbase[NBKT], cur[NBKT];
  __shared__ uint2 recs[CHUNK];
  const int t = threadIdx.x;
  const long e0 = (long)blockIdx.x * CHUNK;
  const int cnt = (EE - e0 < CHUNK) ? (int)(EE - e0) : CHUNK;
  for (int i = t; i < NBKT; i += 256) hist[i] = 0;
  __syncthreads();
  for (int i = t; i < cnt; i += 256) {
    int d = dst[e0 + i];
    atomicAdd(&hist[d >> BSHIFT], 1u);
  }
  __syncthreads();
  if (t == 0) {
    uint run = 0;
    for (int i = 0; i < NBKT; ++i) { excl[i] = run; run += hist[i]; }
  }
  __syncthreads();
  if (t < NBKT) {
    gbase[t] = atomicAdd(&bcnt[t], hist[t]);
    cur[t] = excl[t];
  }
  __syncthreads();
  for (int i = t; i < cnt; i += 256) {
    uint s = (uint)src[e0 + i], d = (uint)dst[e0 + i];
    uint p = atomicAdd(&cur[d >> BSHIFT], 1u);
    recs[p] = make_uint2(s, d);
  }
  __syncthreads();
  for (int i = t; i < cnt; i += 256) {
    uint2 r = recs[i];
    uint b = r.y >> BSHIFT;
    uint pos = gbase[b] + ((uint)i - excl[b]);
    if (pos < CAP) tmp[(long)b * CAP + pos] = r.x | ((r.y & 511u) << 17);
  }
}

__global__ __launch_bounds__(256) void k_bscan(const uint* __restrict__ bcnt,
    uint* __restrict__ bbase, int* __restrict__ indptr) {
  __shared__ uint lds[NBKT];
  int t = threadIdx.x;
  if (t < NBKT) lds[t] = bcnt[t];
  __syncthreads();
  if (t == 0) {
    uint run = 0;
    for (int i = 0; i < NBKT; ++i) { bbase[i] = run; run += lds[i]; }
    indptr[NN] = (int)run;
  }
}

__global__ __launch_bounds__(256) void k_partB(const uint* __restrict__ bcnt,
    const uint* __restrict__ bbase, const uint* __restrict__ tmp,
    int* __restrict__ indptr, int* __restrict__ ssrc, int* __restrict__ sdst) {
  __shared__ uint hist[512], cur[512], wsum[256];
  __shared__ uint stage[CAP];
  const int b = blockIdx.x, t = threadIdx.x;
  const int dlo = b << BSHIFT;
  const int nn = (NN - dlo < 512) ? (NN - dlo) : 512;
  int nrec = (int)bcnt[b];
  if (nrec > CAP) nrec = CAP;
  const uint base = bbase[b];
  const uint* tb = tmp + (long)b * CAP;
  for (int i = t; i < 512; i += 256) hist[i] = 0;
  __syncthreads();
  for (int i = t; i < nrec; i += 256) {
    atomicAdd(&hist[tb[i] >> 17], 1u);
  }
  __syncthreads();
  uint a0 = hist[t * 2], a1 = hist[t * 2 + 1];
  uint ts = a0 + a1;
  wsum[t] = ts;
  __syncthreads();
  for (int st = 1; st < 256; st <<= 1) {
    uint v = (t >= st) ? wsum[t - st] : 0;
    __syncthreads();
    wsum[t] += v;
    __syncthreads();
  }
  uint texcl = wsum[t] - ts;
  cur[t * 2] = texcl;
  cur[t * 2 + 1] = texcl + a0;
  if (t * 2 < nn)     indptr[dlo + t * 2]     = (int)(base + texcl);
  if (t * 2 + 1 < nn) indptr[dlo + t * 2 + 1] = (int)(base + texcl + a0);
  __syncthreads();
  for (int i = t; i < nrec; i += 256) {
    uint v = tb[i];
    uint rel = atomicAdd(&cur[v >> 17], 1u);
    stage[rel] = v;
  }
  __syncthreads();
  for (int i = t; i < nrec; i += 256) {
    uint v = stage[i];
    ssrc[base + i] = (int)(v & 0x1FFFFu);
    sdst[base + i] = dlo + (int)(v >> 17);
  }
}

// ------------- fused GAT layer: 16 lanes/edge, 4 edges/iter, fp8 dwordx2 gather -------------
// lane quarter q = lane>>4 owns edge 4*kk+q; each lane holds 8 elems (bytes 8*l4..8*l4+7).
// w loads: SGPR-advancing base + loop-invariant lane offset. Peeled <=3-edge tail.
template<int HEADS, bool FINAL, bool PREVBF>
__global__ __launch_bounds__(256) void gat_aggregate(
    const int* __restrict__ indptr, const int* __restrict__ ssrc,
    const float* __restrict__ wcsr, const char* __restrict__ feat8,
    const float* __restrict__ bias, const void* __restrict__ prevv,
    const float* __restrict__ g, const float* __restrict__ beta,
    void* __restrict__ outv, int N) {
  int wave = threadIdx.x >> 6, lane = threadIdx.x & 63;
  long n = (long)blockIdx.x * 4 + wave;
  if (n >= N) return;
  const int b = __builtin_amdgcn_readfirstlane(indptr[n]);
  const int e = __builtin_amdgcn_readfirstlane(indptr[n + 1]);
  const int deg = e - b;
  const int l4 = lane & 15, q = lane >> 4;
  const int head = (HEADS == 4) ? (l4 >> 2) : 0;
  const int* sp = ssrc + b;                                  // uniform -> scalar loads
  const float* wl = wcsr + (size_t)b * HEADS + q * HEADS + head;  // + 4*HEADS per kk
  const uint lpart = (uint)l4 * 8u;

  f32x2 ac0 = {0.f, 0.f}, ac1 = {0.f, 0.f}, ac2 = {0.f, 0.f}, ac3 = {0.f, 0.f};
  float s = 0.f;
  const int ngrp = deg >> 2;
#pragma unroll 2
  for (int kk = 0; kk < ngrp; ++kk) {
    int sn0 = sp[4 * kk + 0], sn1 = sp[4 * kk + 1];
    int sn2 = sp[4 * kk + 2], sn3 = sp[4 * kk + 3];
    uint so0 = (uint)sn0 << 7, so1 = (uint)sn1 << 7;
    uint so2 = (uint)sn2 << 7, so3 = (uint)sn3 << 7;
    uint so = (q == 0) ? so0 : (q == 1) ? so1 : (q == 2) ? so2 : so3;
    uint2 v = *(const uint2*)(feat8 + (so + lpart));
    float w = wl[(size_t)kk * 4 * HEADS];
    s += w;
    f32x2 w2 = {w, w};
    ac0 += w2 * __builtin_amdgcn_cvt_pk_f32_fp8((int)v.x, false);
    ac1 += w2 * __builtin_amdgcn_cvt_pk_f32_fp8((int)v.x, true);
    ac2 += w2 * __builtin_amdgcn_cvt_pk_f32_fp8((int)v.y, false);
    ac3 += w2 * __builtin_amdgcn_cvt_pk_f32_fp8((int)v.y, true);
  }
  // tail: edges 4*ngrp .. deg-1 (<=3), per-lane predicated
  if (deg & 3) {
    int j = 4 * ngrp + q;
    int jc = j < deg - 1 ? j : deg - 1;
    uint sn = (uint)ssrc[b + jc];                 // vector gather (once)
    uint2 v = *(const uint2*)(feat8 + (((uint)sn << 7) + lpart));
    float w = wcsr[(size_t)(b + jc) * HEADS + head];
    w = (j < deg) ? w : 0.f;
    s += w;
    f32x2 w2 = {w, w};
    ac0 += w2 * __builtin_amdgcn_cvt_pk_f32_fp8((int)v.x, false);
    ac1 += w2 * __builtin_amdgcn_cvt_pk_f32_fp8((int)v.x, true);
    ac2 += w2 * __builtin_amdgcn_cvt_pk_f32_fp8((int)v.y, false);
    ac3 += w2 * __builtin_amdgcn_cvt_pk_f32_fp8((int)v.y, true);
  }
  // combine lane-quarters (xor 16, 32)
#pragma unroll
  for (int m = 16; m <= 32; m <<= 1) {
    ac0[0] += __shfl_xor(ac0[0], m, 64); ac0[1] += __shfl_xor(ac0[1], m, 64);
    ac1[0] += __shfl_xor(ac1[0], m, 64); ac1[1] += __shfl_xor(ac1[1], m, 64);
    ac2[0] += __shfl_xor(ac2[0], m, 64); ac2[1] += __shfl_xor(ac2[1], m, 64);
    ac3[0] += __shfl_xor(ac3[0], m, 64); ac3[1] += __shfl_xor(ac3[1], m, 64);
    s += __shfl_xor(s, m, 64);
  }

  float inv = (s > 0.f) ? 1.f / s : 0.f;
  float v0 = ac0[0] * inv, v1 = ac0[1] * inv, v2 = ac1[0] * inv, v3 = ac1[1] * inv;
  float v4 = ac2[0] * inv, v5 = ac2[1] * inv, v6 = ac3[0] * inv, v7 = ac3[1] * inv;
  float4 bl = ((const float4*)bias)[l4 * 2];
  float4 bh = ((const float4*)bias)[l4 * 2 + 1];
  v0 += bl.x; v1 += bl.y; v2 += bl.z; v3 += bl.w;
  v4 += bh.x; v5 += bh.y; v6 += bh.z; v7 += bh.w;
  if (!FINAL) {
    v0 = v0 > 0.f ? v0 : __expf(v0) - 1.f;
    v1 = v1 > 0.f ? v1 : __expf(v1) - 1.f;
    v2 = v2 > 0.f ? v2 : __expf(v2) - 1.f;
    v3 = v3 > 0.f ? v3 : __expf(v3) - 1.f;
    v4 = v4 > 0.f ? v4 : __expf(v4) - 1.f;
    v5 = v5 > 0.f ? v5 : __expf(v5) - 1.f;
    v6 = v6 > 0.f ? v6 : __expf(v6) - 1.f;
    v7 = v7 > 0.f ? v7 : __expf(v7) - 1.f;
  }
  if (PREVBF) {
    uint4 pp = ((const uint4*)prevv)[n * 16 + l4];
    v0 += bflo(pp.x); v1 += bfhi(pp.x);
    v2 += bflo(pp.y); v3 += bfhi(pp.y);
    v4 += bflo(pp.z); v5 += bfhi(pp.z);
    v6 += bflo(pp.w); v7 += bfhi(pp.w);
  } else {
    float4 pl = ((const float4*)prevv)[n * 32 + l4 * 2];
    float4 ph = ((const float4*)prevv)[n * 32 + l4 * 2 + 1];
    v0 += pl.x; v1 += pl.y; v2 += pl.z; v3 += pl.w;
    v4 += ph.x; v5 += ph.y; v6 += ph.z; v7 += ph.w;
  }
  if (!FINAL) {
    float sum = ((v0 + v1) + (v2 + v3)) + ((v4 + v5) + (v6 + v7));
#pragma unroll
    for (int m = 8; m; m >>= 1) sum += __shfl_xor(sum, m, 64);
    float mu = sum * (1.f / 128.f);
    float d0 = v0 - mu, d1 = v1 - mu, d2 = v2 - mu, d3 = v3 - mu;
    float d4 = v4 - mu, d5 = v5 - mu, d6 = v6 - mu, d7 = v7 - mu;
    float vs = ((d0 * d0 + d1 * d1) + (d2 * d2 + d3 * d3)) +
               ((d4 * d4 + d5 * d5) + (d6 * d6 + d7 * d7));
#pragma unroll
    for (int m = 8; m; m >>= 1) vs += __shfl_xor(vs, m, 64);
    float rstd = rsqrtf(vs * (1.f / 128.f) + 1e-5f);
    float4 g4l = ((const float4*)g)[l4 * 2];
    float4 g4h = ((const float4*)g)[l4 * 2 + 1];
    float4 bel = ((const float4*)beta)[l4 * 2];
    float4 beh = ((const float4*)beta)[l4 * 2 + 1];
    float o0 = d0 * rstd * g4l.x + bel.x;
    float o1 = d1 * rstd * g4l.y + bel.y;
    float o2 = d2 * rstd * g4l.z + bel.z;
    float o3 = d3 * rstd * g4l.w + bel.w;
    float o4 = d4 * rstd * g4h.x + beh.x;
    float o5 = d5 * rstd * g4h.y + beh.y;
    float o6 = d6 * rstd * g4h.z + beh.z;
    float o7 = d7 * rstd * g4h.w + beh.w;
    if (q == 0) {
      uint4 ov;
      ov.x = pack2bf(o0, o1); ov.y = pack2bf(o2, o3);
      ov.z = pack2bf(o4, o5); ov.w = pack2bf(o6, o7);
      ((uint4*)outv)[n * 16 + l4] = ov;
    }
  } else {
    if (q == 0) ((float4*)outv)[n * 32 + l4 * 2] = make_float4(v0, v1, v2, v3);
    if (q == 1) ((float4*)outv)[n * 32 + l4 * 2 + 1] = make_float4(v4, v5, v6, v7);
  }
}

extern "C" void kernel_launch(void* const* d_in, const int* in_sizes, int n_in,
                              void* d_out, int out_size, void* d_ws, size_t ws_size,
                              hipStream_t stream) {
  const float* x   = (const float*)d_in[0];
  const int*   src = (const int*)d_in[1];
  const int*   dst = (const int*)d_in[2];
  const float* W0  = (const float*)d_in[3];
  const float* al0 = (const float*)d_in[4];
  const float* ar0 = (const float*)d_in[5];
  const float* b0  = (const float*)d_in[6];
  const float* W1  = (const float*)d_in[7];
  const float* al1 = (const float*)d_in[8];
  const float* ar1 = (const float*)d_in[9];
  const float* b1  = (const float*)d_in[10];
  const float* W2  = (const float*)d_in[11];
  const float* al2 = (const float*)d_in[12];
  const float* ar2 = (const float*)d_in[13];
  const float* b2  = (const float*)d_in[14];
  const float* g0  = (const float*)d_in[15];
  const float* be0 = (const float*)d_in[16];
  const float* g1  = (const float*)d_in[17];
  const float* be1 = (const float*)d_in[18];
  const float* Wc  = (const float*)d_in[19];
  const float* bc  = (const float*)d_in[20];

  float* out    = (float*)d_out;
  float* logits = out;                     // [N,64]
  float* emb    = out + (long)NN * 64;     // [N,128]

  // workspace
  char*   feat8 = (char*)d_ws;                          // N*128 fp8 (value table)
  float*  el    = (float*)(feat8 + (size_t)NN * 128);   // N*4
  float*  er    = el + (long)NN * 4;                    // N*4
  ushort* bufAb = (ushort*)(er + (long)NN * 4);         // N*128 bf16 hidden
  ushort* bufBb = bufAb + (long)NN * 128;               // N*128 bf16 hidden
  float*  wcsrb = (float*)(bufBb + (long)NN * 128);     // E*4 f32
  int*    sdst  = (int*)(wcsrb + (long)EE * 4);         // E
  uint*   tmp   = (uint*)(sdst + EE);                   // NBKT*CAP uint
  uint*   bcnt  = tmp + (long)NBKT * CAP;               // NBKT
  uint*   bbase = bcnt + NBKT;                          // NBKT
  ushort* feat8s = (ushort*)feat8;

  // CSR (indptr + ssrc) in logits region (overwritten by classifier at the end)
  int* indptr = (int*)d_out;               // N+1
  int* ssrc   = indptr + NN + 1;           // E

  const int gN4 = (NN + 3) / 4;            // 25000
  const int gGm = (NN + 127) / 128;        // 782
  const int gE  = (EE + 255) / 256;        // 6250

  // ---- CSR build ----
  hipMemsetAsync(bcnt, 0, NBKT * sizeof(uint), stream);
  k_partA<<<NBLKA, 256, 0, stream>>>(src, dst, bcnt, tmp);
  k_bscan<<<1, 256, 0, stream>>>(bcnt, bbase, indptr);
  k_partB<<<NBKT, 256, 0, stream>>>(bcnt, bbase, tmp, indptr, ssrc, sdst);

  // ---- layer 0 ----
  gemm_mfma<128, false, 4><<<gGm, 256, 0, stream>>>(x, W0, nullptr, nullptr, feat8s, al0, ar0, el, er, NN);
  wcomp<4><<<gE, 256, 0, stream>>>(ssrc, sdst, el, er, wcsrb);
  gat_aggregate<4, false, false><<<gN4, 256, 0, stream>>>(indptr, ssrc, wcsrb, feat8, b0, x, g0, be0, bufAb, NN);

  // ---- layer 1 ----
  gemm_mfma<128, true, 4><<<gGm, 256, 0, stream>>>(bufAb, W1, nullptr, nullptr, feat8s, al1, ar1, el, er, NN);
  wcomp<4><<<gE, 256, 0, stream>>>(ssrc, sdst, el, er, wcsrb);
  gat_aggregate<4, false, true><<<gN4, 256, 0, stream>>>(indptr, ssrc, wcsrb, feat8, b1, bufAb, g1, be1, bufBb, NN);

  // ---- layer 2 (heads=1, no act/LN) ----
  gemm_mfma<128, true, 1><<<gGm, 256, 0, stream>>>(bufBb, W2, nullptr, nullptr, feat8s, al2, ar2, el, er, NN);
  wcomp<1><<<gE, 256, 0, stream>>>(ssrc, sdst, el, er, wcsrb);
  gat_aggregate<1, true, true><<<gN4, 256, 0, stream>>>(indptr, ssrc, wcsrb, feat8, b2, bufBb, nullptr, nullptr, emb, NN);

  // ---- classifier ----
  gemm_mfma<64, false, 0><<<gGm, 256, 0, stream>>>(emb, Wc, bc, logits, nullptr, nullptr, nullptr, nullptr, nullptr, NN);
}

// Round 13
// 337.109 us; speedup vs baseline: 1.1554x; 1.1554x over previous
//
#include <hip/hip_runtime.h>

#define NN 100000
#define EE 1600000
#define BSHIFT 9
#define NBKT ((NN + 511) / 512)          // 196
#define CAP 10240                         // per-bucket capacity (avg 8163)
#define CHUNK 2048
#define NBLKA ((EE + CHUNK - 1) / CHUNK)  // 782

typedef float f32x4 __attribute__((ext_vector_type(4)));
typedef float f32x2 __attribute__((ext_vector_type(2)));
typedef short s16x8 __attribute__((ext_vector_type(8)));

__device__ __forceinline__ ushort f2bf(float x) {      // f32 -> bf16 bits, RNE
  uint u = __float_as_uint(x);
  return (ushort)((u + 0x7fffu + ((u >> 16) & 1u)) >> 16);
}
__device__ __forceinline__ uint pack2bf(float x, float y) {
  return (uint)f2bf(x) | ((uint)f2bf(y) << 16);
}
__device__ __forceinline__ float bflo(uint p) { return __uint_as_float(p << 16); }
__device__ __forceinline__ float bfhi(uint p) { return __uint_as_float(p & 0xffff0000u); }

// ---------------- MFMA GEMM: A[N,128] @ W[128,M] ----------------
// ELER==0: write f32 out + bias (classifier).
// ELER>0 : stage tile in LDS -> fused el/er (ELER heads) + fp8 e4m3 feat table.
template<int M, bool ABF, int ELER>
__global__ __launch_bounds__(256) void gemm_mfma(const void* __restrict__ Av,
    const float* __restrict__ W, const float* __restrict__ bias,
    float* __restrict__ outf, ushort* __restrict__ feat8s,
    const float* __restrict__ al, const float* __restrict__ ar,
    float* __restrict__ el, float* __restrict__ er, int N) {
  __shared__ ushort Wt[M * 136];                 // W^T bf16; reused as output stage for ELER
  const int tid = threadIdx.x;
  for (int idx = tid; idx < 128 * M; idx += 256) {
    int k = idx / M, c = idx - k * M;
    Wt[c * 136 + k] = f2bf(W[idx]);
  }
  __syncthreads();
  const int wid = tid >> 6, lane = tid & 63;
  const int rl = lane & 15, grp = lane >> 4;
  const long row0 = (long)blockIdx.x * 128;

  s16x8 af[2][4];
#pragma unroll
  for (int rt = 0; rt < 2; ++rt) {
    long row = row0 + rt * 64 + wid * 16 + rl;
    if (row >= N) row = N - 1;
    if (ABF) {
      const s16x8* Ar = (const s16x8*)((const ushort*)Av + row * 128);
#pragma unroll
      for (int ks = 0; ks < 4; ++ks) af[rt][ks] = Ar[ks * 4 + grp];
    } else {
      const float4* Ar = (const float4*)((const float*)Av + row * 128);
#pragma unroll
      for (int ks = 0; ks < 4; ++ks) {
        float4 a0 = Ar[ks * 8 + grp * 2];
        float4 a1 = Ar[ks * 8 + grp * 2 + 1];
        s16x8 f;
        f[0] = (short)f2bf(a0.x); f[1] = (short)f2bf(a0.y);
        f[2] = (short)f2bf(a0.z); f[3] = (short)f2bf(a0.w);
        f[4] = (short)f2bf(a1.x); f[5] = (short)f2bf(a1.y);
        f[6] = (short)f2bf(a1.z); f[7] = (short)f2bf(a1.w);
        af[rt][ks] = f;
      }
    }
  }
  const int NT = M / 16;
  f32x4 acc[2][NT];
#pragma unroll
  for (int rt = 0; rt < 2; ++rt)
#pragma unroll
    for (int ct = 0; ct < NT; ++ct) acc[rt][ct] = (f32x4)(0.f);

#pragma unroll
  for (int ct = 0; ct < NT; ++ct) {
#pragma unroll
    for (int ks = 0; ks < 4; ++ks) {
      s16x8 bf = *(const s16x8*)&Wt[(ct * 16 + rl) * 136 + ks * 32 + grp * 8];
      acc[0][ct] = __builtin_amdgcn_mfma_f32_16x16x32_bf16(af[0][ks], bf, acc[0][ct], 0, 0, 0);
      acc[1][ct] = __builtin_amdgcn_mfma_f32_16x16x32_bf16(af[1][ks], bf, acc[1][ct], 0, 0, 0);
    }
  }

  if (ELER > 0) __syncthreads();   // everyone done reading Wt before reuse as stage

#pragma unroll
  for (int rt = 0; rt < 2; ++rt) {
#pragma unroll
    for (int ct = 0; ct < NT; ++ct) {
      int col = ct * 16 + rl;
      float bb = (ELER == 0) ? bias[col] : 0.f;
#pragma unroll
      for (int j = 0; j < 4; ++j) {
        int lrow = rt * 64 + wid * 16 + grp * 4 + j;
        long grow = row0 + lrow;
        if (ELER > 0) {
          Wt[lrow * 128 + col] = f2bf(acc[rt][ct][j]);   // stage only
        } else if (grow < N) {
          outf[grow * M + col] = acc[rt][ct][j] + bb;
        }
      }
    }
  }

  if (ELER > 0) {
    __syncthreads();
    const uint* stage = (const uint*)Wt;           // [128][64] packed bf16 pairs
    float2 a2 = ((const float2*)al)[lane];
    float2 r2 = ((const float2*)ar)[lane];
    for (int rr = 0; rr < 32; ++rr) {
      int lrow = wid * 32 + rr;
      long grow = row0 + lrow;
      uint p = stage[lrow * 64 + lane];
      float x0 = bflo(p), x1 = bfhi(p);
      int pk8 = __builtin_amdgcn_cvt_pk_fp8_f32(x0, x1, 0, false);
      if (grow < N) feat8s[grow * 64 + lane] = (ushort)pk8;
      float pl = x0 * a2.x + x1 * a2.y;
      float pr = x0 * r2.x + x1 * r2.y;
      if (ELER == 4) {
#pragma unroll
        for (int m = 8; m; m >>= 1) {
          pl += __shfl_xor(pl, m, 16);
          pr += __shfl_xor(pr, m, 16);
        }
        if ((lane & 15) == 0 && grow < N) {
          el[grow * 4 + (lane >> 4)] = pl;
          er[grow * 4 + (lane >> 4)] = pr;
        }
      } else {
#pragma unroll
        for (int m = 32; m; m >>= 1) {
          pl += __shfl_xor(pl, m, 64);
          pr += __shfl_xor(pr, m, 64);
        }
        if (lane == 0 && grow < N) { el[grow] = pl; er[grow] = pr; }
      }
    }
  }
}

// ---------------- CSR build: bucketed counting sort (packed 32-bit records) ----------------
__global__ __launch_bounds__(256) void k_partA(const int* __restrict__ src,
    const int* __restrict__ dst, uint* __restrict__ bcnt, uint* __restrict__ tmp) {
  __shared__ uint hist[NBKT], excl[NBKT], gbase[NBKT], cur[NBKT];
  __shared__ uint2 recs[CHUNK];
  const int t = threadIdx.x;
  const long e0 = (long)blockIdx.x * CHUNK;
  const int cnt = (EE - e0 < CHUNK) ? (int)(EE - e0) : CHUNK;
  for (int i = t; i < NBKT; i += 256) hist[i] = 0;
  __syncthreads();
  for (int i = t; i < cnt; i += 256) {
    int d = dst[e0 + i];
    atomicAdd(&hist[d >> BSHIFT], 1u);
  }
  __syncthreads();
  if (t == 0) {
    uint run = 0;
    for (int i = 0; i < NBKT; ++i) { excl[i] = run; run += hist[i]; }
  }
  __syncthreads();
  if (t < NBKT) {
    gbase[t] = atomicAdd(&bcnt[t], hist[t]);
    cur[t] = excl[t];
  }
  __syncthreads();
  for (int i = t; i < cnt; i += 256) {
    uint s = (uint)src[e0 + i], d = (uint)dst[e0 + i];
    uint p = atomicAdd(&cur[d >> BSHIFT], 1u);
    recs[p] = make_uint2(s, d);
  }
  __syncthreads();
  for (int i = t; i < cnt; i += 256) {
    uint2 r = recs[i];
    uint b = r.y >> BSHIFT;
    uint pos = gbase[b] + ((uint)i - excl[b]);
    if (pos < CAP) tmp[(long)b * CAP + pos] = r.x | ((r.y & 511u) << 17);
  }
}

__global__ __launch_bounds__(256) void k_bscan(const uint* __restrict__ bcnt,
    uint* __restrict__ bbase, int* __restrict__ indptr) {
  __shared__ uint lds[NBKT];
  int t = threadIdx.x;
  if (t < NBKT) lds[t] = bcnt[t];
  __syncthreads();
  if (t == 0) {
    uint run = 0;
    for (int i = 0; i < NBKT; ++i) { bbase[i] = run; run += lds[i]; }
    indptr[NN] = (int)run;
  }
}

__global__ __launch_bounds__(256) void k_partB(const uint* __restrict__ bcnt,
    const uint* __restrict__ bbase, const uint* __restrict__ tmp,
    int* __restrict__ indptr, int* __restrict__ ssrc) {
  __shared__ uint hist[512], cur[512], wsum[256];
  __shared__ uint stage[CAP];
  const int b = blockIdx.x, t = threadIdx.x;
  const int dlo = b << BSHIFT;
  const int nn = (NN - dlo < 512) ? (NN - dlo) : 512;
  int nrec = (int)bcnt[b];
  if (nrec > CAP) nrec = CAP;
  const uint base = bbase[b];
  const uint* tb = tmp + (long)b * CAP;
  for (int i = t; i < 512; i += 256) hist[i] = 0;
  __syncthreads();
  for (int i = t; i < nrec; i += 256) {
    atomicAdd(&hist[tb[i] >> 17], 1u);
  }
  __syncthreads();
  uint a0 = hist[t * 2], a1 = hist[t * 2 + 1];
  uint ts = a0 + a1;
  wsum[t] = ts;
  __syncthreads();
  for (int st = 1; st < 256; st <<= 1) {
    uint v = (t >= st) ? wsum[t - st] : 0;
    __syncthreads();
    wsum[t] += v;
    __syncthreads();
  }
  uint texcl = wsum[t] - ts;
  cur[t * 2] = texcl;
  cur[t * 2 + 1] = texcl + a0;
  if (t * 2 < nn)     indptr[dlo + t * 2]     = (int)(base + texcl);
  if (t * 2 + 1 < nn) indptr[dlo + t * 2 + 1] = (int)(base + texcl + a0);
  __syncthreads();
  for (int i = t; i < nrec; i += 256) {
    uint v = tb[i];
    uint rel = atomicAdd(&cur[v >> 17], 1u);
    stage[rel] = v;
  }
  __syncthreads();
  for (int i = t; i < nrec; i += 256) {
    ssrc[base + i] = (int)(stage[i] & 0x1FFFFu);
  }
}

// ------------- fused GAT layer: paired-edge fp8 gather + in-loop attention weights -------------
// lanes 0-31 = edge a, 32-63 = edge b; each lane holds 4 fp8 elems (one dword).
// w = exp(leaky(el[src]+er[n])) computed in-loop (el table is L2-resident; one exp
// wave-inst covers both edges). Halves combined at the end via shfl_xor(·,32).
template<int HEADS, bool FINAL, bool PREVBF>
__global__ __launch_bounds__(256) void gat_aggregate(
    const int* __restrict__ indptr, const int* __restrict__ ssrc,
    const char* __restrict__ el8, const float* __restrict__ er,
    const char* __restrict__ feat8, const float* __restrict__ bias,
    const void* __restrict__ prevv, const float* __restrict__ g,
    const float* __restrict__ beta, void* __restrict__ outv,
    ushort* __restrict__ embb, int N) {
  int wave = threadIdx.x >> 6, lane = threadIdx.x & 63;
  long n = (long)blockIdx.x * 4 + wave;
  if (n >= N) return;
  const int b = __builtin_amdgcn_readfirstlane(indptr[n]);
  const int e = __builtin_amdgcn_readfirstlane(indptr[n + 1]);
  const int deg = e - b;
  const int l5 = lane & 31, half = lane >> 5;
  const int head = (HEADS == 4) ? (l5 >> 3) : 0;
  const float er0 = (HEADS == 4) ? er[n * 4 + head] : er[n];
  const int* sp = ssrc + b;                       // uniform -> scalar loads
  const uint lpart = (uint)l5 * 4u;
  const uint hoff = (uint)head * 4u;

  float a0 = 0.f, a1 = 0.f, a2 = 0.f, a3 = 0.f, s = 0.f;
  const int npair = (deg + 1) >> 1;
  for (int p = 0; p < npair; p += 4) {
#pragma unroll
    for (int k = 0; k < 4; ++k) {
      const int pk = p + k;
      int ja = 2 * pk;     if (ja > deg - 1) ja = deg - 1;   // scalar clamp
      int jb = 2 * pk + 1; if (jb > deg - 1) jb = deg - 1;
      uint sna = (uint)sp[ja], snb = (uint)sp[jb];
      uint fo = ((half ? snb : sna) << 7) + lpart;
      uint v = *(const uint*)(feat8 + fo);        // 4 fp8 elems of my edge
      float elv;
      if (HEADS == 4) elv = *(const float*)(el8 + (((half ? snb : sna) << 4) + hoff));
      else            elv = *(const float*)(el8 + ((half ? snb : sna) << 2));
      float ev = elv + er0;
      ev = fmaxf(ev, 0.f) + 0.2f * fminf(ev, 0.f);
      float w = __expf(ev);
      w = (2 * pk + half < deg) ? w : 0.f;        // per-edge validity
      auto f01 = __builtin_amdgcn_cvt_pk_f32_fp8((int)v, false);
      auto f23 = __builtin_amdgcn_cvt_pk_f32_fp8((int)v, true);
      s += w;
      a0 = fmaf(w, f01[0], a0);
      a1 = fmaf(w, f01[1], a1);
      a2 = fmaf(w, f23[0], a2);
      a3 = fmaf(w, f23[1], a3);
    }
  }
  // combine edge-halves
  a0 += __shfl_xor(a0, 32, 64);
  a1 += __shfl_xor(a1, 32, 64);
  a2 += __shfl_xor(a2, 32, 64);
  a3 += __shfl_xor(a3, 32, 64);
  s  += __shfl_xor(s, 32, 64);

  float inv = (s > 0.f) ? 1.f / s : 0.f;
  float v0 = a0 * inv, v1 = a1 * inv, v2 = a2 * inv, v3 = a3 * inv;
  float4 bb = ((const float4*)bias)[l5];
  v0 += bb.x; v1 += bb.y; v2 += bb.z; v3 += bb.w;
  if (!FINAL) {
    v0 = v0 > 0.f ? v0 : __expf(v0) - 1.f;
    v1 = v1 > 0.f ? v1 : __expf(v1) - 1.f;
    v2 = v2 > 0.f ? v2 : __expf(v2) - 1.f;
    v3 = v3 > 0.f ? v3 : __expf(v3) - 1.f;
  }
  if (PREVBF) {
    uint2 pp = ((const uint2*)prevv)[n * 32 + l5];
    v0 += bflo(pp.x); v1 += bfhi(pp.x);
    v2 += bflo(pp.y); v3 += bfhi(pp.y);
  } else {
    float4 ph = ((const float4*)prevv)[n * 32 + l5];
    v0 += ph.x; v1 += ph.y; v2 += ph.z; v3 += ph.w;
  }
  if (!FINAL) {
    float sum = v0 + v1 + v2 + v3;
#pragma unroll
    for (int m = 16; m; m >>= 1) sum += __shfl_xor(sum, m, 64);
    float mu = sum * (1.f / 128.f);
    float d0 = v0 - mu, d1 = v1 - mu, d2 = v2 - mu, d3 = v3 - mu;
    float vs = d0 * d0 + d1 * d1 + d2 * d2 + d3 * d3;
#pragma unroll
    for (int m = 16; m; m >>= 1) vs += __shfl_xor(vs, m, 64);
    float rstd = rsqrtf(vs * (1.f / 128.f) + 1e-5f);
    float4 g4 = ((const float4*)g)[l5];
    float4 be4 = ((const float4*)beta)[l5];
    float o0 = d0 * rstd * g4.x + be4.x;
    float o1 = d1 * rstd * g4.y + be4.y;
    float o2 = d2 * rstd * g4.z + be4.z;
    float o3 = d3 * rstd * g4.w + be4.w;
    if (!half) ((uint2*)outv)[n * 32 + l5] = make_uint2(pack2bf(o0, o1), pack2bf(o2, o3));
  } else {
    if (!half) {
      ((float4*)outv)[n * 32 + l5] = make_float4(v0, v1, v2, v3);
      ((uint2*)embb)[n * 32 + l5] = make_uint2(pack2bf(v0, v1), pack2bf(v2, v3));
    }
  }
}

extern "C" void kernel_launch(void* const* d_in, const int* in_sizes, int n_in,
                              void* d_out, int out_size, void* d_ws, size_t ws_size,
                              hipStream_t stream) {
  const float* x   = (const float*)d_in[0];
  const int*   src = (const int*)d_in[1];
  const int*   dst = (const int*)d_in[2];
  const float* W0  = (const float*)d_in[3];
  const float* al0 = (const float*)d_in[4];
  const float* ar0 = (const float*)d_in[5];
  const float* b0  = (const float*)d_in[6];
  const float* W1  = (const float*)d_in[7];
  const float* al1 = (const float*)d_in[8];
  const float* ar1 = (const float*)d_in[9];
  const float* b1  = (const float*)d_in[10];
  const float* W2  = (const float*)d_in[11];
  const float* al2 = (const float*)d_in[12];
  const float* ar2 = (const float*)d_in[13];
  const float* b2  = (const float*)d_in[14];
  const float* g0  = (const float*)d_in[15];
  const float* be0 = (const float*)d_in[16];
  const float* g1  = (const float*)d_in[17];
  const float* be1 = (const float*)d_in[18];
  const float* Wc  = (const float*)d_in[19];
  const float* bc  = (const float*)d_in[20];

  float* out    = (float*)d_out;
  float* logits = out;                     // [N,64]
  float* emb    = out + (long)NN * 64;     // [N,128]

  // workspace
  char*   feat8 = (char*)d_ws;                          // N*128 fp8 (value table)
  float*  el    = (float*)(feat8 + (size_t)NN * 128);   // N*4
  float*  er    = el + (long)NN * 4;                    // N*4
  ushort* bufAb = (ushort*)(er + (long)NN * 4);         // N*128 bf16 hidden
  ushort* bufBb = bufAb + (long)NN * 128;               // N*128 bf16 hidden
  uint*   tmp   = (uint*)(bufBb + (long)NN * 128);      // NBKT*CAP uint
  uint*   bcnt  = tmp + (long)NBKT * CAP;               // NBKT
  uint*   bbase = bcnt + NBKT;                          // NBKT
  ushort* feat8s = (ushort*)feat8;
  char*   el8   = (char*)el;

  // CSR (indptr + ssrc) in logits region (overwritten by classifier at the end)
  int* indptr = (int*)d_out;               // N+1
  int* ssrc   = indptr + NN + 1;           // E

  const int gN4 = (NN + 3) / 4;            // 25000
  const int gGm = (NN + 127) / 128;        // 782

  // ---- CSR build ----
  hipMemsetAsync(bcnt, 0, NBKT * sizeof(uint), stream);
  k_partA<<<NBLKA, 256, 0, stream>>>(src, dst, bcnt, tmp);
  k_bscan<<<1, 256, 0, stream>>>(bcnt, bbase, indptr);
  k_partB<<<NBKT, 256, 0, stream>>>(bcnt, bbase, tmp, indptr, ssrc);

  // ---- layer 0 ----
  gemm_mfma<128, false, 4><<<gGm, 256, 0, stream>>>(x, W0, nullptr, nullptr, feat8s, al0, ar0, el, er, NN);
  gat_aggregate<4, false, false><<<gN4, 256, 0, stream>>>(indptr, ssrc, el8, er, feat8, b0, x, g0, be0, bufAb, nullptr, NN);

  // ---- layer 1 ----
  gemm_mfma<128, true, 4><<<gGm, 256, 0, stream>>>(bufAb, W1, nullptr, nullptr, feat8s, al1, ar1, el, er, NN);
  gat_aggregate<4, false, true><<<gN4, 256, 0, stream>>>(indptr, ssrc, el8, er, feat8, b1, bufAb, g1, be1, bufBb, nullptr, NN);

  // ---- layer 2 (heads=1, no act/LN; writes f32 emb + bf16 copy into bufAb) ----
  gemm_mfma<128, true, 1><<<gGm, 256, 0, stream>>>(bufBb, W2, nullptr, nullptr, feat8s, al2, ar2, el, er, NN);
  gat_aggregate<1, true, true><<<gN4, 256, 0, stream>>>(indptr, ssrc, el8, er, feat8, b2, bufBb, nullptr, nullptr, emb, bufAb, NN);

  // ---- classifier (bf16 emb copy as A) ----
  gemm_mfma<64, true, 0><<<gGm, 256, 0, stream>>>(bufAb, Wc, bc, logits, nullptr, nullptr, nullptr, nullptr, nullptr, NN);
}